// Round 11
// baseline (49.397 us; speedup 1.0000x reference)
//
#include <hip/hip_runtime.h>

// STDP learner: per-row decayed trace scan + scatter-add into vocab + clip.
// B=1024 rows, S=8192 steps, VOCAB=128000.
//
// Measured decomposition (R8/R9 duplicate-dispatch attribution):
//   scan 19.4 us | bin ~17 us | reduce+overhead ~10 us.
// bin is at the LDS-atomic mechanism floor (~4 cyc/lane serialized:
//   2.5M atomics/256 CU ~= 16.4 us) -- R10's reg-staging + occupancy were null.
// R11: scan loads go coalesced->LDS->contiguous (kills the 64B/lane stride
// that thrashed L1); bin reverted to G2=32 (R10's G2=64 doubled partials).

#define VOCAB_N 128000
#define B_ROWS  1024
#define S_LEN   8192
#define NRANGE  8
#define VR      16000          // vocab bins per range (62.5 KB LDS histogram)
#define VR2     (VR / 2)       // packed bf16x2 columns per range
#define G2      32             // partial-histogram blocks per range
#define CAP     512            // slots per (range,row); E[count]=307, +12 sigma
#define ROWS_PER_BIN (B_ROWS / G2)   // 32

constexpr float TRACE_DECAY = 0.8187307530779818586699355f;  // exp(-1/5)
constexpr float A16 = 0.040762203978366211696f;              // TRACE_DECAY^16
constexpr float LR_PLUS = 0.01f;
constexpr float W_DECAY = 0.99f;

__device__ __forceinline__ unsigned f32_to_bf16_rtne(float x) {
    unsigned b = __float_as_uint(x);
    b += 0x7FFFu + ((b >> 16) & 1u);
    return b >> 16;
}

// ---------------- Kernel 1: scan + pack into deterministic segments --------
// One block (512 threads = 8 waves) per row; 16 contiguous timesteps/thread.
// Loads: coalesced global float4 -> LDS (transposed layout) -> per-thread
// contiguous ds_read_b128. Transpose layout: float4 #m at slot (m&3)*256+(m>>2)
// so thread c's four float4s (m=4c..4c+3) sit at slots {j*256+c} -- the READ
// side is lane-contiguous (conflict-free b128); write side is 8 instrs/wave.
__global__ __launch_bounds__(512) void stdp_scan_pack(
    const int* __restrict__ token_ids,
    const float* __restrict__ spikes,
    unsigned* __restrict__ counts,    // [B_ROWS][NRANGE]
    unsigned* __restrict__ pairs)     // [NRANGE][B_ROWS][CAP]
{
    const int row  = blockIdx.x;
    const int tid  = threadIdx.x;
    const int lane = tid & 63;
    const int wid  = tid >> 6;   // 0..7

    __shared__ float4   tbuf[1024];            // 16 KB transpose buffer
    __shared__ float    wAf[8], wBf[8];
    __shared__ unsigned long long wlo[8], whi[8];
    __shared__ unsigned bcnt[NRANGE];
    __shared__ unsigned stage[NRANGE][CAP];    // 16 KB pair staging

    float s[16];
    int   tok[16];

    // ---- Staged transpose load of spikes (two half-rows through tbuf).
    {
        const float4* sp4 = reinterpret_cast<const float4*>(spikes) +
                            (size_t)row * (S_LEN / 4);
        #pragma unroll
        for (int h = 0; h < 2; ++h) {
            // stage: 1024 float4 = 2 coalesced rounds
            #pragma unroll
            for (int k = 0; k < 2; ++k) {
                int m = k * 512 + tid;                 // local float4 idx
                tbuf[(m & 3) * 256 + (m >> 2)] = sp4[h * 1024 + m];
            }
            __syncthreads();
            if ((tid >> 8) == h) {                     // 256 owning threads
                int c = tid & 255;
                #pragma unroll
                for (int j = 0; j < 4; ++j) {
                    float4 q = tbuf[j * 256 + c];
                    s[4 * j + 0] = q.x; s[4 * j + 1] = q.y;
                    s[4 * j + 2] = q.z; s[4 * j + 3] = q.w;
                }
            }
            __syncthreads();
        }
    }
    // ---- Same for tokens (reuse tbuf as int4).
    {
        int4* ibuf = reinterpret_cast<int4*>(tbuf);
        const int4* tk4 = reinterpret_cast<const int4*>(token_ids) +
                          (size_t)row * (S_LEN / 4);
        #pragma unroll
        for (int h = 0; h < 2; ++h) {
            #pragma unroll
            for (int k = 0; k < 2; ++k) {
                int m = k * 512 + tid;
                ibuf[(m & 3) * 256 + (m >> 2)] = tk4[h * 1024 + m];
            }
            __syncthreads();
            if ((tid >> 8) == h) {
                int c = tid & 255;
                #pragma unroll
                for (int j = 0; j < 4; ++j) {
                    int4 q = ibuf[j * 256 + c];
                    tok[4 * j + 0] = q.x; tok[4 * j + 1] = q.y;
                    tok[4 * j + 2] = q.z; tok[4 * j + 3] = q.w;
                }
            }
            __syncthreads();
        }
    }

    // ---- Local affine reduction: state_out = A16*state_in + L.
    float L = 0.f;
    #pragma unroll
    for (int j = 0; j < 16; ++j) L = fmaf(L, TRACE_DECAY, s[j]);

    // ---- Per-item ranges (4-bit packed) + per-range counts (2x u64,
    //      16-bit fields, 4 ranges each).
    unsigned long long rpack = 0ull, cnt_lo = 0ull, cnt_hi = 0ull;
    #pragma unroll
    for (int j = 0; j < 16; ++j) {
        int r = tok[j] / VR;                       // 0..7 (magic-mul div)
        rpack |= (unsigned long long)r << (4 * j);
        if (s[j] != 0.f) {
            if (r < 4) cnt_lo += 1ull << (r << 4);
            else       cnt_hi += 1ull << ((r - 4) << 4);
        }
    }

    // ---- Kogge-Stone wave scans: f32 affine pair + u64 count vectors.
    float A = A16, Bv = L;
    unsigned long long ilo = cnt_lo, ihi = cnt_hi;
    #pragma unroll
    for (int o = 1; o < 64; o <<= 1) {
        float Ao = __shfl_up(A, o);
        float Bo = __shfl_up(Bv, o);
        unsigned long long ulo = __shfl_up(ilo, o);
        unsigned long long uhi = __shfl_up(ihi, o);
        if (lane >= o) { Bv = fmaf(A, Bo, Bv); A = A * Ao; ilo += ulo; ihi += uhi; }
    }

    // ---- Cross-wave fixup for both scans around one barrier.
    if (lane == 63) { wAf[wid] = A; wBf[wid] = Bv; wlo[wid] = ilo; whi[wid] = ihi; }
    __syncthreads();

    float carry = 0.f;
    unsigned long long blo = 0ull, bhi = 0ull;
    #pragma unroll
    for (int w = 0; w < 7; ++w)
        if (w < wid) {
            carry = fmaf(wAf[w], carry, wBf[w]);
            blo += wlo[w]; bhi += whi[w];
        }

    // f32 exclusive value = incoming trace for this thread's chunk.
    float Ae = __shfl_up(A, 1), Be = __shfl_up(Bv, 1);
    if (lane == 0) { Ae = 1.f; Be = 0.f; }
    float trace = fmaf(Ae, carry, Be);

    // u64 exclusive rank within block, packed per range.
    unsigned long long offlo = (ilo - cnt_lo) + blo;
    unsigned long long offhi = (ihi - cnt_hi) + bhi;

    // ---- Per-(row,range) totals: plain stores, no atomics.
    if (tid < NRANGE) {
        unsigned long long t = 0ull;
        unsigned c;
        if (tid < 4) {
            #pragma unroll
            for (int w = 0; w < 8; ++w) t += wlo[w];
            c = (unsigned)((t >> (tid * 16)) & 0xFFFFull);
        } else {
            #pragma unroll
            for (int w = 0; w < 8; ++w) t += whi[w];
            c = (unsigned)((t >> ((tid - 4) * 16)) & 0xFFFFull);
        }
        counts[row * NRANGE + tid] = c;
        bcnt[tid] = c > CAP ? CAP : c;
    }

    // ---- Pass B: replay recurrence, pack (bf16 | 17-bit token) into LDS
    //      stage at the block-deterministic rank.
    {
        float tr = trace;
        #pragma unroll
        for (int j = 0; j < 16; ++j) {
            tr = fmaf(tr, TRACE_DECAY, s[j]);
            if (s[j] != 0.f) {
                float upd = LR_PLUS * tr;                   // in (0, 0.054]
                unsigned pk = (f32_to_bf16_rtne(upd) << 17) | (unsigned)tok[j];
                int r = (int)((rpack >> (4 * j)) & 0xFull);
                unsigned slot;
                if (r < 4) {
                    int sh = r << 4;
                    slot = (unsigned)((offlo >> sh) & 0xFFFFull);
                    offlo += 1ull << sh;
                } else {
                    int sh = (r - 4) << 4;
                    slot = (unsigned)((offhi >> sh) & 0xFFFFull);
                    offhi += 1ull << sh;
                }
                if (slot < CAP) stage[r][slot] = pk;
                // slot >= CAP: dropped (statistically impossible, +12 sigma)
            }
        }
    }
    __syncthreads();

    // ---- Coalesced dump: 8 contiguous segments (valid prefix only).
    #pragma unroll
    for (int k = 0; k < (NRANGE * CAP) / 512; ++k) {   // 8 iters
        int idx = k * 512 + tid;
        int r = idx >> 9;            // /CAP
        int i = idx & (CAP - 1);
        if ((unsigned)i < bcnt[r])
            pairs[((size_t)r * B_ROWS + row) * CAP + i] = stage[r][i];
    }
}

// ---------------- Kernel 2: per-range LDS histogram -> bf16x2 partials -----
// Block (r,g) processes rows [g*32, g*32+32) of range r; pair data is one
// contiguous 64 KB region staged in registers (8 uint4/thread). 512 threads.
// At the LDS-atomic mechanism floor (~16.5 us chip-wide) -- do not re-tune.
__global__ __launch_bounds__(512) void stdp_bin(
    const unsigned* __restrict__ counts,   // [B_ROWS][NRANGE]
    const unsigned* __restrict__ pairs,    // [NRANGE][B_ROWS][CAP]
    unsigned* __restrict__ part)           // [NRANGE][G2][VR2] bf16x2
{
    __shared__ float bins[VR];                 // 62.5 KB
    __shared__ unsigned ccache[ROWS_PER_BIN];
    const int r = blockIdx.x >> 5;   // / G2
    const int g = blockIdx.x & (G2 - 1);
    const int row0 = g * ROWS_PER_BIN;

    // Block region: ROWS_PER_BIN*CAP = 16384 u32 = 4096 uint4; 8 per thread.
    const uint4* bp4 = reinterpret_cast<const uint4*>(
        pairs + ((size_t)r * B_ROWS + row0) * CAP);
    uint4 q[8];
    #pragma unroll
    for (int i = 0; i < 8; ++i) q[i] = bp4[threadIdx.x + 512 * i];

    float4* b4 = reinterpret_cast<float4*>(bins);
    for (int i = threadIdx.x; i < VR / 4; i += 512)
        b4[i] = make_float4(0.f, 0.f, 0.f, 0.f);
    if (threadIdx.x < ROWS_PER_BIN) {
        unsigned c = counts[(row0 + threadIdx.x) * NRANGE + r];
        ccache[threadIdx.x] = c > CAP ? CAP : c;
    }
    __syncthreads();

    const int rbase = r * VR;
    #pragma unroll
    for (int i = 0; i < 8; ++i) {
        int idx4 = (int)threadIdx.x + 512 * i;
        int rr = idx4 >> 7;                  // /(CAP/4)
        unsigned i0 = (idx4 & 127) << 2;     // slot of .x
        unsigned c = ccache[rr];
        unsigned pv[4] = {q[i].x, q[i].y, q[i].z, q[i].w};
        #pragma unroll
        for (int sub = 0; sub < 4; ++sub) {
            if (i0 + sub < c) {
                unsigned p = pv[sub];
                int t = (int)(p & 0x1FFFFu) - rbase;
                float v = __uint_as_float((p >> 17) << 16);
                atomicAdd(&bins[t], v);      // LDS atomic (ds_add_f32)
            }
        }
    }
    __syncthreads();

    // Pack two adjacent f32 bins into one bf16x2 word (lo = even bin).
    unsigned* o = part + ((size_t)(r * G2 + g)) * VR2;
    for (int i = threadIdx.x; i < VR2; i += 512) {
        unsigned lo = f32_to_bf16_rtne(bins[2 * i]);
        unsigned hi = f32_to_bf16_rtne(bins[2 * i + 1]);
        o[i] = lo | (hi << 16);
    }
}

// ---------------- Kernel 3: reduce bf16x2 partials + clip ------------------
// One packed column (2 vocab entries) per thread; 250 blocks x 256 threads.
__global__ __launch_bounds__(256) void stdp_reduce(
    const float* __restrict__ token_weights,
    const unsigned* __restrict__ part,     // [NRANGE][G2][VR2]
    float* __restrict__ out)
{
    int c = blockIdx.x * 256 + threadIdx.x;        // 0 .. VOCAB_N/2-1
    if (c >= VOCAB_N / 2) return;
    int r = c / VR2;
    int l = c - r * VR2;
    const unsigned* p = part + (size_t)r * G2 * VR2 + l;
    float a0 = 0.f, a1 = 0.f;
    #pragma unroll
    for (int g = 0; g < G2; ++g) {
        unsigned u = p[(size_t)g * VR2];
        a0 += __uint_as_float(u << 16);
        a1 += __uint_as_float(u & 0xFFFF0000u);
    }
    float2 w = reinterpret_cast<const float2*>(token_weights)[c];
    float2 o;
    o.x = fminf(fmaxf((w.x + a0) * W_DECAY, 0.f), 1.f);
    o.y = fminf(fmaxf((w.y + a1) * W_DECAY, 0.f), 1.f);
    reinterpret_cast<float2*>(out)[c] = o;
}

// ---------------- Fallback path (round-2, correct but 139 us) --------------
__global__ __launch_bounds__(512) void stdp_scan_scatter(
    const int* __restrict__ token_ids,
    const float* __restrict__ spikes,
    float* __restrict__ grad)
{
    const int row  = blockIdx.x;
    const int tid  = threadIdx.x;
    const int lane = tid & 63;
    const int wid  = tid >> 6;
    const long base = (long)row * S_LEN + (long)tid * 16;

    float s[16]; int tok[16];
    {
        const float4* sp4 = reinterpret_cast<const float4*>(spikes + base);
        const int4*   tk4 = reinterpret_cast<const int4*>(token_ids + base);
        float4 a0 = sp4[0], a1 = sp4[1], a2 = sp4[2], a3 = sp4[3];
        int4   b0 = tk4[0], b1 = tk4[1], b2 = tk4[2], b3 = tk4[3];
        s[0]=a0.x; s[1]=a0.y; s[2]=a0.z; s[3]=a0.w;
        s[4]=a1.x; s[5]=a1.y; s[6]=a1.z; s[7]=a1.w;
        s[8]=a2.x; s[9]=a2.y; s[10]=a2.z; s[11]=a2.w;
        s[12]=a3.x; s[13]=a3.y; s[14]=a3.z; s[15]=a3.w;
        tok[0]=b0.x; tok[1]=b0.y; tok[2]=b0.z; tok[3]=b0.w;
        tok[4]=b1.x; tok[5]=b1.y; tok[6]=b1.z; tok[7]=b1.w;
        tok[8]=b2.x; tok[9]=b2.y; tok[10]=b2.z; tok[11]=b2.w;
        tok[12]=b3.x; tok[13]=b3.y; tok[14]=b3.z; tok[15]=b3.w;
    }

    float L = 0.f;
    #pragma unroll
    for (int j = 0; j < 16; ++j) L = fmaf(L, TRACE_DECAY, s[j]);
    float A = A16, Bv = L;
    #pragma unroll
    for (int o = 1; o < 64; o <<= 1) {
        float Ao = __shfl_up(A, o);
        float Bo = __shfl_up(Bv, o);
        if (lane >= o) { Bv = fmaf(A, Bo, Bv); A = A * Ao; }
    }
    __shared__ float wA[8], wB[8];
    if (lane == 63) { wA[wid] = A; wB[wid] = Bv; }
    __syncthreads();
    float carry = 0.f;
    #pragma unroll
    for (int w = 0; w < 7; ++w)
        if (w < wid) carry = fmaf(wA[w], carry, wB[w]);
    float Ae = __shfl_up(A, 1), Be = __shfl_up(Bv, 1);
    if (lane == 0) { Ae = 1.f; Be = 0.f; }
    float trace = fmaf(Ae, carry, Be);

    #pragma unroll
    for (int j = 0; j < 16; ++j) {
        trace = fmaf(trace, TRACE_DECAY, s[j]);
        if (s[j] != 0.f) atomicAdd(&grad[tok[j]], LR_PLUS * trace);
    }
}

__global__ __launch_bounds__(256) void stdp_finalize(
    const float* __restrict__ token_weights,
    float* __restrict__ out, int n)
{
    int v = blockIdx.x * 256 + threadIdx.x;
    if (v < n) {
        float g = out[v];
        float w = (token_weights[v] + g) * W_DECAY;
        out[v] = fminf(fmaxf(w, 0.f), 1.f);
    }
}

// ---------------- Host launcher -------------------------------------------
extern "C" void kernel_launch(void* const* d_in, const int* in_sizes, int n_in,
                              void* d_out, int out_size, void* d_ws, size_t ws_size,
                              hipStream_t stream) {
    const int*   token_ids = (const int*)d_in[0];
    const float* spikes    = (const float*)d_in[1];
    const float* tw        = (const float*)d_in[2];
    float* out = (float*)d_out;

    // Workspace layout:
    //   [counts: B*NRANGE u32] [pairs: NRANGE*B*CAP u32] [part: NRANGE*G2*VR2 u32]
    const size_t counts_elems = (size_t)B_ROWS * NRANGE;                // 8192
    const size_t pairs_elems  = (size_t)NRANGE * B_ROWS * CAP;         // 4.19M
    const size_t part_elems   = (size_t)NRANGE * G2 * VR2;             // 2.05M
    const size_t need = (counts_elems + pairs_elems + part_elems) * 4; // 25 MB

    if (ws_size >= need) {
        unsigned* counts = (unsigned*)d_ws;
        unsigned* pairs  = counts + counts_elems;
        unsigned* part   = pairs + pairs_elems;

        stdp_scan_pack<<<B_ROWS, 512, 0, stream>>>(token_ids, spikes,
                                                   counts, pairs);
        stdp_bin<<<NRANGE * G2, 512, 0, stream>>>(counts, pairs, part);
        stdp_reduce<<<(VOCAB_N / 2 + 255) / 256, 256, 0, stream>>>(tw, part, out);
    } else {
        // Fallback: direct global atomics.
        hipMemsetAsync(out, 0, (size_t)out_size * sizeof(float), stream);
        stdp_scan_scatter<<<B_ROWS, 512, 0, stream>>>(token_ids, spikes, out);
        stdp_finalize<<<(out_size + 255) / 256, 256, 0, stream>>>(tw, out,
                                                                  out_size);
    }
}

// Round 12
// 41.035 us; speedup vs baseline: 1.2038x; 1.2038x over previous
//
#include <hip/hip_runtime.h>

// STDP learner: per-row decayed trace scan + scatter-add into vocab + clip.
// B=1024 rows, S=8192 steps, VOCAB=128000.
//
// Measured decomposition (duplicate-dispatch attribution R8/R9):
//   scan 19.4 us | bin 17.0 us | reduce+gaps ~10 us.  Best total: R7 46.36.
// R11 (LDS-transpose scan loads) regressed -> reverted; scan = R7 form.
// R12: bin histogram switched from ds_add_f32 to fixed-point ds_add_u32
//      (units of 2^-24) -- isolates whether the f32 LDS atomic op is the
//      17us mechanism. Everything else identical to R7.

#define VOCAB_N 128000
#define B_ROWS  1024
#define S_LEN   8192
#define NRANGE  8
#define VR      16000          // vocab bins per range (62.5 KB LDS histogram)
#define VR2     (VR / 2)       // packed bf16x2 columns per range
#define G2      32             // partial-histogram blocks per range
#define CAP     512            // slots per (range,row); E[count]=307, +12 sigma
#define ROWS_PER_BIN (B_ROWS / G2)   // 32

constexpr float TRACE_DECAY = 0.8187307530779818586699355f;  // exp(-1/5)
constexpr float A16 = 0.040762203978366211696f;              // TRACE_DECAY^16
constexpr float LR_PLUS = 0.01f;
constexpr float W_DECAY = 0.99f;
constexpr float FXP_SCALE = 16777216.f;      // 2^24
constexpr float FXP_INV   = 5.9604644775390625e-8f;  // 2^-24

__device__ __forceinline__ unsigned f32_to_bf16_rtne(float x) {
    unsigned b = __float_as_uint(x);
    b += 0x7FFFu + ((b >> 16) & 1u);
    return b >> 16;
}

// ---------------- Kernel 1: scan + pack into deterministic segments --------
// One block (512 threads = 8 waves) per row; 16 contiguous timesteps/thread.
__global__ __launch_bounds__(512) void stdp_scan_pack(
    const int* __restrict__ token_ids,
    const float* __restrict__ spikes,
    unsigned* __restrict__ counts,    // [B_ROWS][NRANGE]
    unsigned* __restrict__ pairs)     // [NRANGE][B_ROWS][CAP]
{
    const int row  = blockIdx.x;
    const int tid  = threadIdx.x;
    const int lane = tid & 63;
    const int wid  = tid >> 6;   // 0..7
    const long base = (long)row * S_LEN + (long)tid * 16;

    float s[16];
    int   tok[16];
    {
        const float4* sp4 = reinterpret_cast<const float4*>(spikes + base);
        const int4*   tk4 = reinterpret_cast<const int4*>(token_ids + base);
        float4 a0 = sp4[0], a1 = sp4[1], a2 = sp4[2], a3 = sp4[3];
        int4   b0 = tk4[0], b1 = tk4[1], b2 = tk4[2], b3 = tk4[3];
        s[0]=a0.x; s[1]=a0.y; s[2]=a0.z; s[3]=a0.w;
        s[4]=a1.x; s[5]=a1.y; s[6]=a1.z; s[7]=a1.w;
        s[8]=a2.x; s[9]=a2.y; s[10]=a2.z; s[11]=a2.w;
        s[12]=a3.x; s[13]=a3.y; s[14]=a3.z; s[15]=a3.w;
        tok[0]=b0.x; tok[1]=b0.y; tok[2]=b0.z; tok[3]=b0.w;
        tok[4]=b1.x; tok[5]=b1.y; tok[6]=b1.z; tok[7]=b1.w;
        tok[8]=b2.x; tok[9]=b2.y; tok[10]=b2.z; tok[11]=b2.w;
        tok[12]=b3.x; tok[13]=b3.y; tok[14]=b3.z; tok[15]=b3.w;
    }

    // ---- Local affine reduction: state_out = A16*state_in + L.
    float L = 0.f;
    #pragma unroll
    for (int j = 0; j < 16; ++j) L = fmaf(L, TRACE_DECAY, s[j]);

    // ---- Per-item ranges (4-bit packed) + per-range counts (2x u64,
    //      16-bit fields, 4 ranges each).
    unsigned long long rpack = 0ull, cnt_lo = 0ull, cnt_hi = 0ull;
    #pragma unroll
    for (int j = 0; j < 16; ++j) {
        int r = tok[j] / VR;                       // 0..7 (magic-mul div)
        rpack |= (unsigned long long)r << (4 * j);
        if (s[j] != 0.f) {
            if (r < 4) cnt_lo += 1ull << (r << 4);
            else       cnt_hi += 1ull << ((r - 4) << 4);
        }
    }

    // ---- Kogge-Stone wave scans: f32 affine pair + u64 count vectors.
    float A = A16, Bv = L;
    unsigned long long ilo = cnt_lo, ihi = cnt_hi;
    #pragma unroll
    for (int o = 1; o < 64; o <<= 1) {
        float Ao = __shfl_up(A, o);
        float Bo = __shfl_up(Bv, o);
        unsigned long long ulo = __shfl_up(ilo, o);
        unsigned long long uhi = __shfl_up(ihi, o);
        if (lane >= o) { Bv = fmaf(A, Bo, Bv); A = A * Ao; ilo += ulo; ihi += uhi; }
    }

    // ---- Cross-wave fixup for both scans around one barrier.
    __shared__ float wAf[8], wBf[8];
    __shared__ unsigned long long wlo[8], whi[8];
    __shared__ unsigned bcnt[NRANGE];
    __shared__ unsigned stage[NRANGE][CAP];    // 16 KB staging for pair writes
    if (lane == 63) { wAf[wid] = A; wBf[wid] = Bv; wlo[wid] = ilo; whi[wid] = ihi; }
    __syncthreads();

    float carry = 0.f;
    unsigned long long blo = 0ull, bhi = 0ull;
    #pragma unroll
    for (int w = 0; w < 7; ++w)
        if (w < wid) {
            carry = fmaf(wAf[w], carry, wBf[w]);
            blo += wlo[w]; bhi += whi[w];
        }

    // f32 exclusive value = incoming trace for this thread's chunk.
    float Ae = __shfl_up(A, 1), Be = __shfl_up(Bv, 1);
    if (lane == 0) { Ae = 1.f; Be = 0.f; }
    float trace = fmaf(Ae, carry, Be);

    // u64 exclusive rank within block, packed per range.
    unsigned long long offlo = (ilo - cnt_lo) + blo;
    unsigned long long offhi = (ihi - cnt_hi) + bhi;

    // ---- Per-(row,range) totals: plain stores, no atomics.
    if (tid < NRANGE) {
        unsigned long long t = 0ull;
        unsigned c;
        if (tid < 4) {
            #pragma unroll
            for (int w = 0; w < 8; ++w) t += wlo[w];
            c = (unsigned)((t >> (tid * 16)) & 0xFFFFull);
        } else {
            #pragma unroll
            for (int w = 0; w < 8; ++w) t += whi[w];
            c = (unsigned)((t >> ((tid - 4) * 16)) & 0xFFFFull);
        }
        counts[row * NRANGE + tid] = c;
        bcnt[tid] = c > CAP ? CAP : c;
    }

    // ---- Pass B: replay recurrence, pack (bf16 | 17-bit token) into LDS
    //      stage at the block-deterministic rank.
    {
        float tr = trace;
        #pragma unroll
        for (int j = 0; j < 16; ++j) {
            tr = fmaf(tr, TRACE_DECAY, s[j]);
            if (s[j] != 0.f) {
                float upd = LR_PLUS * tr;                   // in (0, 0.054]
                unsigned pk = (f32_to_bf16_rtne(upd) << 17) | (unsigned)tok[j];
                int r = (int)((rpack >> (4 * j)) & 0xFull);
                unsigned slot;
                if (r < 4) {
                    int sh = r << 4;
                    slot = (unsigned)((offlo >> sh) & 0xFFFFull);
                    offlo += 1ull << sh;
                } else {
                    int sh = (r - 4) << 4;
                    slot = (unsigned)((offhi >> sh) & 0xFFFFull);
                    offhi += 1ull << sh;
                }
                if (slot < CAP) stage[r][slot] = pk;
                // slot >= CAP: dropped (statistically impossible, +12 sigma)
            }
        }
    }
    __syncthreads();

    // ---- Coalesced dump: 8 contiguous segments (valid prefix only).
    #pragma unroll
    for (int k = 0; k < (NRANGE * CAP) / 512; ++k) {   // 8 iters
        int idx = k * 512 + tid;
        int r = idx >> 9;            // /CAP
        int i = idx & (CAP - 1);
        if ((unsigned)i < bcnt[r])
            pairs[((size_t)r * B_ROWS + row) * CAP + i] = stage[r][i];
    }
}

// ---------------- Kernel 2: per-range LDS histogram -> bf16x2 partials -----
// Block (r,g) processes rows [g*32, g*32+32) of range r; contiguous 64 KB
// pair region. 512 threads. R12: u32 fixed-point accumulation (ds_add_u32,
// units of 2^-24) instead of ds_add_f32 -- atomic-mechanism isolation.
__global__ __launch_bounds__(512) void stdp_bin(
    const unsigned* __restrict__ counts,   // [B_ROWS][NRANGE]
    const unsigned* __restrict__ pairs,    // [NRANGE][B_ROWS][CAP]
    unsigned* __restrict__ part)           // [NRANGE][G2][VR2] bf16x2
{
    __shared__ unsigned bins[VR];              // 62.5 KB, fixed-point 2^-24
    __shared__ unsigned ccache[ROWS_PER_BIN];
    const int r = blockIdx.x >> 5;   // / G2
    const int g = blockIdx.x & 31;
    const int row0 = g * ROWS_PER_BIN;

    uint4* b4 = reinterpret_cast<uint4*>(bins);
    for (int i = threadIdx.x; i < VR / 4; i += 512)
        b4[i] = make_uint4(0u, 0u, 0u, 0u);
    if (threadIdx.x < ROWS_PER_BIN) {
        unsigned c = counts[(row0 + threadIdx.x) * NRANGE + r];
        ccache[threadIdx.x] = c > CAP ? CAP : c;
    }
    __syncthreads();

    const unsigned* bp = pairs + ((size_t)r * B_ROWS + row0) * CAP;
    const int rbase = r * VR;
    #pragma unroll 4
    for (int idx = threadIdx.x; idx < ROWS_PER_BIN * CAP; idx += 512) {
        int rr = idx >> 9;           // / CAP
        int i  = idx & (CAP - 1);
        if ((unsigned)i < ccache[rr]) {
            unsigned p = bp[idx];
            int t = (int)(p & 0x1FFFFu) - rbase;
            float v = __uint_as_float((p >> 17) << 16);
            unsigned q = __float2uint_rn(v * FXP_SCALE);
            atomicAdd(&bins[t], q);            // ds_add_u32
        }
    }
    __syncthreads();

    // Pack two adjacent fixed-point bins into one bf16x2 word (lo = even bin).
    unsigned* o = part + ((size_t)(r * G2 + g)) * VR2;
    for (int i = threadIdx.x; i < VR2; i += 512) {
        unsigned lo = f32_to_bf16_rtne((float)bins[2 * i]     * FXP_INV);
        unsigned hi = f32_to_bf16_rtne((float)bins[2 * i + 1] * FXP_INV);
        o[i] = lo | (hi << 16);
    }
}

// ---------------- Kernel 3: reduce bf16x2 partials + clip ------------------
// One packed column (2 vocab entries) per thread; 250 blocks x 256 threads.
__global__ __launch_bounds__(256) void stdp_reduce(
    const float* __restrict__ token_weights,
    const unsigned* __restrict__ part,     // [NRANGE][G2][VR2]
    float* __restrict__ out)
{
    int c = blockIdx.x * 256 + threadIdx.x;        // 0 .. VOCAB_N/2-1
    if (c >= VOCAB_N / 2) return;
    int r = c / VR2;
    int l = c - r * VR2;
    const unsigned* p = part + (size_t)r * G2 * VR2 + l;
    float a0 = 0.f, a1 = 0.f;
    #pragma unroll
    for (int g = 0; g < G2; ++g) {
        unsigned u = p[(size_t)g * VR2];
        a0 += __uint_as_float(u << 16);
        a1 += __uint_as_float(u & 0xFFFF0000u);
    }
    float2 w = reinterpret_cast<const float2*>(token_weights)[c];
    float2 o;
    o.x = fminf(fmaxf((w.x + a0) * W_DECAY, 0.f), 1.f);
    o.y = fminf(fmaxf((w.y + a1) * W_DECAY, 0.f), 1.f);
    reinterpret_cast<float2*>(out)[c] = o;
}

// ---------------- Fallback path (round-2, correct but 139 us) --------------
__global__ __launch_bounds__(512) void stdp_scan_scatter(
    const int* __restrict__ token_ids,
    const float* __restrict__ spikes,
    float* __restrict__ grad)
{
    const int row  = blockIdx.x;
    const int tid  = threadIdx.x;
    const int lane = tid & 63;
    const int wid  = tid >> 6;
    const long base = (long)row * S_LEN + (long)tid * 16;

    float s[16]; int tok[16];
    {
        const float4* sp4 = reinterpret_cast<const float4*>(spikes + base);
        const int4*   tk4 = reinterpret_cast<const int4*>(token_ids + base);
        float4 a0 = sp4[0], a1 = sp4[1], a2 = sp4[2], a3 = sp4[3];
        int4   b0 = tk4[0], b1 = tk4[1], b2 = tk4[2], b3 = tk4[3];
        s[0]=a0.x; s[1]=a0.y; s[2]=a0.z; s[3]=a0.w;
        s[4]=a1.x; s[5]=a1.y; s[6]=a1.z; s[7]=a1.w;
        s[8]=a2.x; s[9]=a2.y; s[10]=a2.z; s[11]=a2.w;
        s[12]=a3.x; s[13]=a3.y; s[14]=a3.z; s[15]=a3.w;
        tok[0]=b0.x; tok[1]=b0.y; tok[2]=b0.z; tok[3]=b0.w;
        tok[4]=b1.x; tok[5]=b1.y; tok[6]=b1.z; tok[7]=b1.w;
        tok[8]=b2.x; tok[9]=b2.y; tok[10]=b2.z; tok[11]=b2.w;
        tok[12]=b3.x; tok[13]=b3.y; tok[14]=b3.z; tok[15]=b3.w;
    }

    float L = 0.f;
    #pragma unroll
    for (int j = 0; j < 16; ++j) L = fmaf(L, TRACE_DECAY, s[j]);
    float A = A16, Bv = L;
    #pragma unroll
    for (int o = 1; o < 64; o <<= 1) {
        float Ao = __shfl_up(A, o);
        float Bo = __shfl_up(Bv, o);
        if (lane >= o) { Bv = fmaf(A, Bo, Bv); A = A * Ao; }
    }
    __shared__ float wA[8], wB[8];
    if (lane == 63) { wA[wid] = A; wB[wid] = Bv; }
    __syncthreads();
    float carry = 0.f;
    #pragma unroll
    for (int w = 0; w < 7; ++w)
        if (w < wid) carry = fmaf(wA[w], carry, wB[w]);
    float Ae = __shfl_up(A, 1), Be = __shfl_up(Bv, 1);
    if (lane == 0) { Ae = 1.f; Be = 0.f; }
    float trace = fmaf(Ae, carry, Be);

    #pragma unroll
    for (int j = 0; j < 16; ++j) {
        trace = fmaf(trace, TRACE_DECAY, s[j]);
        if (s[j] != 0.f) atomicAdd(&grad[tok[j]], LR_PLUS * trace);
    }
}

__global__ __launch_bounds__(256) void stdp_finalize(
    const float* __restrict__ token_weights,
    float* __restrict__ out, int n)
{
    int v = blockIdx.x * 256 + threadIdx.x;
    if (v < n) {
        float g = out[v];
        float w = (token_weights[v] + g) * W_DECAY;
        out[v] = fminf(fmaxf(w, 0.f), 1.f);
    }
}

// ---------------- Host launcher -------------------------------------------
extern "C" void kernel_launch(void* const* d_in, const int* in_sizes, int n_in,
                              void* d_out, int out_size, void* d_ws, size_t ws_size,
                              hipStream_t stream) {
    const int*   token_ids = (const int*)d_in[0];
    const float* spikes    = (const float*)d_in[1];
    const float* tw        = (const float*)d_in[2];
    float* out = (float*)d_out;

    // Workspace layout:
    //   [counts: B*NRANGE u32] [pairs: NRANGE*B*CAP u32] [part: NRANGE*G2*VR2 u32]
    const size_t counts_elems = (size_t)B_ROWS * NRANGE;                // 8192
    const size_t pairs_elems  = (size_t)NRANGE * B_ROWS * CAP;         // 4.19M
    const size_t part_elems   = (size_t)NRANGE * G2 * VR2;             // 2.05M
    const size_t need = (counts_elems + pairs_elems + part_elems) * 4; // 25 MB

    if (ws_size >= need) {
        unsigned* counts = (unsigned*)d_ws;
        unsigned* pairs  = counts + counts_elems;
        unsigned* part   = pairs + pairs_elems;

        stdp_scan_pack<<<B_ROWS, 512, 0, stream>>>(token_ids, spikes,
                                                   counts, pairs);
        stdp_bin<<<NRANGE * G2, 512, 0, stream>>>(counts, pairs, part);
        stdp_reduce<<<(VOCAB_N / 2 + 255) / 256, 256, 0, stream>>>(tw, part, out);
    } else {
        // Fallback: direct global atomics.
        hipMemsetAsync(out, 0, (size_t)out_size * sizeof(float), stream);
        stdp_scan_scatter<<<B_ROWS, 512, 0, stream>>>(token_ids, spikes, out);
        stdp_finalize<<<(out_size + 255) / 256, 256, 0, stream>>>(tw, out,
                                                                  out_size);
    }
}

// Round 13
// 40.932 us; speedup vs baseline: 1.2068x; 1.0025x over previous
//
#include <hip/hip_runtime.h>

// STDP learner: per-row decayed trace scan + scatter-add into vocab + clip.
// B=1024 rows, S=8192 steps, VOCAB=128000.
//
// Measured ledger (duplicate-dispatch attribution + A/B rounds):
//   scan 19.4 us | bin 11.6 us (u32 LDS atomics; f32 was +5.4) | reduce ~3
//   | graph/dispatch overhead ~7.  R12 total: 41.0 us.
// bin's atomic phase ~= LDS issue-rate floor (2.5M ds ops/256 CU*2cyc~=8us).
// R13: scan dump -> unconditional uint4 copy (bin masks by counts, so
// garbage beyond the valid prefix is never read); bcnt removed.

#define VOCAB_N 128000
#define B_ROWS  1024
#define S_LEN   8192
#define NRANGE  8
#define VR      16000          // vocab bins per range (62.5 KB LDS histogram)
#define VR2     (VR / 2)       // packed bf16x2 columns per range
#define G2      32             // partial-histogram blocks per range
#define CAP     512            // slots per (range,row); E[count]=307, +12 sigma
#define ROWS_PER_BIN (B_ROWS / G2)   // 32

constexpr float TRACE_DECAY = 0.8187307530779818586699355f;  // exp(-1/5)
constexpr float A16 = 0.040762203978366211696f;              // TRACE_DECAY^16
constexpr float LR_PLUS = 0.01f;
constexpr float W_DECAY = 0.99f;
constexpr float FXP_SCALE = 16777216.f;              // 2^24
constexpr float FXP_INV   = 5.9604644775390625e-8f;  // 2^-24

__device__ __forceinline__ unsigned f32_to_bf16_rtne(float x) {
    unsigned b = __float_as_uint(x);
    b += 0x7FFFu + ((b >> 16) & 1u);
    return b >> 16;
}

// ---------------- Kernel 1: scan + pack into deterministic segments --------
// One block (512 threads = 8 waves) per row; 16 contiguous timesteps/thread.
__global__ __launch_bounds__(512) void stdp_scan_pack(
    const int* __restrict__ token_ids,
    const float* __restrict__ spikes,
    unsigned* __restrict__ counts,    // [B_ROWS][NRANGE]
    unsigned* __restrict__ pairs)     // [NRANGE][B_ROWS][CAP]
{
    const int row  = blockIdx.x;
    const int tid  = threadIdx.x;
    const int lane = tid & 63;
    const int wid  = tid >> 6;   // 0..7
    const long base = (long)row * S_LEN + (long)tid * 16;

    float s[16];
    int   tok[16];
    {
        const float4* sp4 = reinterpret_cast<const float4*>(spikes + base);
        const int4*   tk4 = reinterpret_cast<const int4*>(token_ids + base);
        float4 a0 = sp4[0], a1 = sp4[1], a2 = sp4[2], a3 = sp4[3];
        int4   b0 = tk4[0], b1 = tk4[1], b2 = tk4[2], b3 = tk4[3];
        s[0]=a0.x; s[1]=a0.y; s[2]=a0.z; s[3]=a0.w;
        s[4]=a1.x; s[5]=a1.y; s[6]=a1.z; s[7]=a1.w;
        s[8]=a2.x; s[9]=a2.y; s[10]=a2.z; s[11]=a2.w;
        s[12]=a3.x; s[13]=a3.y; s[14]=a3.z; s[15]=a3.w;
        tok[0]=b0.x; tok[1]=b0.y; tok[2]=b0.z; tok[3]=b0.w;
        tok[4]=b1.x; tok[5]=b1.y; tok[6]=b1.z; tok[7]=b1.w;
        tok[8]=b2.x; tok[9]=b2.y; tok[10]=b2.z; tok[11]=b2.w;
        tok[12]=b3.x; tok[13]=b3.y; tok[14]=b3.z; tok[15]=b3.w;
    }

    // ---- Local affine reduction: state_out = A16*state_in + L.
    float L = 0.f;
    #pragma unroll
    for (int j = 0; j < 16; ++j) L = fmaf(L, TRACE_DECAY, s[j]);

    // ---- Per-item ranges (4-bit packed) + per-range counts (2x u64,
    //      16-bit fields, 4 ranges each).
    unsigned long long rpack = 0ull, cnt_lo = 0ull, cnt_hi = 0ull;
    #pragma unroll
    for (int j = 0; j < 16; ++j) {
        int r = tok[j] / VR;                       // 0..7 (magic-mul div)
        rpack |= (unsigned long long)r << (4 * j);
        if (s[j] != 0.f) {
            if (r < 4) cnt_lo += 1ull << (r << 4);
            else       cnt_hi += 1ull << ((r - 4) << 4);
        }
    }

    // ---- Kogge-Stone wave scans: f32 affine pair + u64 count vectors.
    float A = A16, Bv = L;
    unsigned long long ilo = cnt_lo, ihi = cnt_hi;
    #pragma unroll
    for (int o = 1; o < 64; o <<= 1) {
        float Ao = __shfl_up(A, o);
        float Bo = __shfl_up(Bv, o);
        unsigned long long ulo = __shfl_up(ilo, o);
        unsigned long long uhi = __shfl_up(ihi, o);
        if (lane >= o) { Bv = fmaf(A, Bo, Bv); A = A * Ao; ilo += ulo; ihi += uhi; }
    }

    // ---- Cross-wave fixup for both scans around one barrier.
    __shared__ float wAf[8], wBf[8];
    __shared__ unsigned long long wlo[8], whi[8];
    __shared__ unsigned stage[NRANGE][CAP];    // 16 KB staging for pair writes
    if (lane == 63) { wAf[wid] = A; wBf[wid] = Bv; wlo[wid] = ilo; whi[wid] = ihi; }
    __syncthreads();

    float carry = 0.f;
    unsigned long long blo = 0ull, bhi = 0ull;
    #pragma unroll
    for (int w = 0; w < 7; ++w)
        if (w < wid) {
            carry = fmaf(wAf[w], carry, wBf[w]);
            blo += wlo[w]; bhi += whi[w];
        }

    // f32 exclusive value = incoming trace for this thread's chunk.
    float Ae = __shfl_up(A, 1), Be = __shfl_up(Bv, 1);
    if (lane == 0) { Ae = 1.f; Be = 0.f; }
    float trace = fmaf(Ae, carry, Be);

    // u64 exclusive rank within block, packed per range.
    unsigned long long offlo = (ilo - cnt_lo) + blo;
    unsigned long long offhi = (ihi - cnt_hi) + bhi;

    // ---- Per-(row,range) totals: plain stores, no atomics.
    if (tid < NRANGE) {
        unsigned long long t = 0ull;
        unsigned c;
        if (tid < 4) {
            #pragma unroll
            for (int w = 0; w < 8; ++w) t += wlo[w];
            c = (unsigned)((t >> (tid * 16)) & 0xFFFFull);
        } else {
            #pragma unroll
            for (int w = 0; w < 8; ++w) t += whi[w];
            c = (unsigned)((t >> ((tid - 4) * 16)) & 0xFFFFull);
        }
        counts[row * NRANGE + tid] = c;
    }

    // ---- Pass B: replay recurrence, pack (bf16 | 17-bit token) into LDS
    //      stage at the block-deterministic rank.
    {
        float tr = trace;
        #pragma unroll
        for (int j = 0; j < 16; ++j) {
            tr = fmaf(tr, TRACE_DECAY, s[j]);
            if (s[j] != 0.f) {
                float upd = LR_PLUS * tr;                   // in (0, 0.054]
                unsigned pk = (f32_to_bf16_rtne(upd) << 17) | (unsigned)tok[j];
                int r = (int)((rpack >> (4 * j)) & 0xFull);
                unsigned slot;
                if (r < 4) {
                    int sh = r << 4;
                    slot = (unsigned)((offlo >> sh) & 0xFFFFull);
                    offlo += 1ull << sh;
                } else {
                    int sh = (r - 4) << 4;
                    slot = (unsigned)((offhi >> sh) & 0xFFFFull);
                    offhi += 1ull << sh;
                }
                if (slot < CAP) stage[r][slot] = pk;
                // slot >= CAP: dropped (statistically impossible, +12 sigma)
            }
        }
    }
    __syncthreads();

    // ---- Unconditional vectorized dump: 1024 uint4, 2 per thread.
    // Slots beyond counts[row][r] contain garbage -- bin never reads them.
    {
        const uint4* st4 = reinterpret_cast<const uint4*>(&stage[0][0]);
        uint4* pr4 = reinterpret_cast<uint4*>(pairs);
        #pragma unroll
        for (int k = 0; k < 2; ++k) {
            int idx4 = k * 512 + tid;
            int r  = idx4 >> 7;              // /(CAP/4)
            int i4 = idx4 & 127;
            pr4[((size_t)r * B_ROWS + row) * (CAP / 4) + i4] = st4[idx4];
        }
    }
}

// ---------------- Kernel 2: per-range LDS histogram -> bf16x2 partials -----
// Block (r,g) processes rows [g*32, g*32+32) of range r; contiguous 64 KB
// pair region. 512 threads. u32 fixed-point accumulation (ds_add_u32,
// units of 2^-24) -- measured 5.4us faster than ds_add_f32 (R12).
__global__ __launch_bounds__(512) void stdp_bin(
    const unsigned* __restrict__ counts,   // [B_ROWS][NRANGE]
    const unsigned* __restrict__ pairs,    // [NRANGE][B_ROWS][CAP]
    unsigned* __restrict__ part)           // [NRANGE][G2][VR2] bf16x2
{
    __shared__ unsigned bins[VR];              // 62.5 KB, fixed-point 2^-24
    __shared__ unsigned ccache[ROWS_PER_BIN];
    const int r = blockIdx.x >> 5;   // / G2
    const int g = blockIdx.x & 31;
    const int row0 = g * ROWS_PER_BIN;

    uint4* b4 = reinterpret_cast<uint4*>(bins);
    for (int i = threadIdx.x; i < VR / 4; i += 512)
        b4[i] = make_uint4(0u, 0u, 0u, 0u);
    if (threadIdx.x < ROWS_PER_BIN) {
        unsigned c = counts[(row0 + threadIdx.x) * NRANGE + r];
        ccache[threadIdx.x] = c > CAP ? CAP : c;
    }
    __syncthreads();

    const unsigned* bp = pairs + ((size_t)r * B_ROWS + row0) * CAP;
    const int rbase = r * VR;
    #pragma unroll 4
    for (int idx = threadIdx.x; idx < ROWS_PER_BIN * CAP; idx += 512) {
        int rr = idx >> 9;           // / CAP
        int i  = idx & (CAP - 1);
        if ((unsigned)i < ccache[rr]) {
            unsigned p = bp[idx];
            int t = (int)(p & 0x1FFFFu) - rbase;
            float v = __uint_as_float((p >> 17) << 16);
            unsigned q = __float2uint_rn(v * FXP_SCALE);
            atomicAdd(&bins[t], q);            // ds_add_u32
        }
    }
    __syncthreads();

    // Pack two adjacent fixed-point bins into one bf16x2 word (lo = even bin).
    unsigned* o = part + ((size_t)(r * G2 + g)) * VR2;
    for (int i = threadIdx.x; i < VR2; i += 512) {
        unsigned lo = f32_to_bf16_rtne((float)bins[2 * i]     * FXP_INV);
        unsigned hi = f32_to_bf16_rtne((float)bins[2 * i + 1] * FXP_INV);
        o[i] = lo | (hi << 16);
    }
}

// ---------------- Kernel 3: reduce bf16x2 partials + clip ------------------
// One packed column (2 vocab entries) per thread; 250 blocks x 256 threads.
__global__ __launch_bounds__(256) void stdp_reduce(
    const float* __restrict__ token_weights,
    const unsigned* __restrict__ part,     // [NRANGE][G2][VR2]
    float* __restrict__ out)
{
    int c = blockIdx.x * 256 + threadIdx.x;        // 0 .. VOCAB_N/2-1
    if (c >= VOCAB_N / 2) return;
    int r = c / VR2;
    int l = c - r * VR2;
    const unsigned* p = part + (size_t)r * G2 * VR2 + l;
    float a0 = 0.f, a1 = 0.f;
    #pragma unroll
    for (int g = 0; g < G2; ++g) {
        unsigned u = p[(size_t)g * VR2];
        a0 += __uint_as_float(u << 16);
        a1 += __uint_as_float(u & 0xFFFF0000u);
    }
    float2 w = reinterpret_cast<const float2*>(token_weights)[c];
    float2 o;
    o.x = fminf(fmaxf((w.x + a0) * W_DECAY, 0.f), 1.f);
    o.y = fminf(fmaxf((w.y + a1) * W_DECAY, 0.f), 1.f);
    reinterpret_cast<float2*>(out)[c] = o;
}

// ---------------- Fallback path (round-2, correct but 139 us) --------------
__global__ __launch_bounds__(512) void stdp_scan_scatter(
    const int* __restrict__ token_ids,
    const float* __restrict__ spikes,
    float* __restrict__ grad)
{
    const int row  = blockIdx.x;
    const int tid  = threadIdx.x;
    const int lane = tid & 63;
    const int wid  = tid >> 6;
    const long base = (long)row * S_LEN + (long)tid * 16;

    float s[16]; int tok[16];
    {
        const float4* sp4 = reinterpret_cast<const float4*>(spikes + base);
        const int4*   tk4 = reinterpret_cast<const int4*>(token_ids + base);
        float4 a0 = sp4[0], a1 = sp4[1], a2 = sp4[2], a3 = sp4[3];
        int4   b0 = tk4[0], b1 = tk4[1], b2 = tk4[2], b3 = tk4[3];
        s[0]=a0.x; s[1]=a0.y; s[2]=a0.z; s[3]=a0.w;
        s[4]=a1.x; s[5]=a1.y; s[6]=a1.z; s[7]=a1.w;
        s[8]=a2.x; s[9]=a2.y; s[10]=a2.z; s[11]=a2.w;
        s[12]=a3.x; s[13]=a3.y; s[14]=a3.z; s[15]=a3.w;
        tok[0]=b0.x; tok[1]=b0.y; tok[2]=b0.z; tok[3]=b0.w;
        tok[4]=b1.x; tok[5]=b1.y; tok[6]=b1.z; tok[7]=b1.w;
        tok[8]=b2.x; tok[9]=b2.y; tok[10]=b2.z; tok[11]=b2.w;
        tok[12]=b3.x; tok[13]=b3.y; tok[14]=b3.z; tok[15]=b3.w;
    }

    float L = 0.f;
    #pragma unroll
    for (int j = 0; j < 16; ++j) L = fmaf(L, TRACE_DECAY, s[j]);
    float A = A16, Bv = L;
    #pragma unroll
    for (int o = 1; o < 64; o <<= 1) {
        float Ao = __shfl_up(A, o);
        float Bo = __shfl_up(Bv, o);
        if (lane >= o) { Bv = fmaf(A, Bo, Bv); A = A * Ao; }
    }
    __shared__ float wA[8], wB[8];
    if (lane == 63) { wA[wid] = A; wB[wid] = Bv; }
    __syncthreads();
    float carry = 0.f;
    #pragma unroll
    for (int w = 0; w < 7; ++w)
        if (w < wid) carry = fmaf(wA[w], carry, wB[w]);
    float Ae = __shfl_up(A, 1), Be = __shfl_up(Bv, 1);
    if (lane == 0) { Ae = 1.f; Be = 0.f; }
    float trace = fmaf(Ae, carry, Be);

    #pragma unroll
    for (int j = 0; j < 16; ++j) {
        trace = fmaf(trace, TRACE_DECAY, s[j]);
        if (s[j] != 0.f) atomicAdd(&grad[tok[j]], LR_PLUS * trace);
    }
}

__global__ __launch_bounds__(256) void stdp_finalize(
    const float* __restrict__ token_weights,
    float* __restrict__ out, int n)
{
    int v = blockIdx.x * 256 + threadIdx.x;
    if (v < n) {
        float g = out[v];
        float w = (token_weights[v] + g) * W_DECAY;
        out[v] = fminf(fmaxf(w, 0.f), 1.f);
    }
}

// ---------------- Host launcher -------------------------------------------
extern "C" void kernel_launch(void* const* d_in, const int* in_sizes, int n_in,
                              void* d_out, int out_size, void* d_ws, size_t ws_size,
                              hipStream_t stream) {
    const int*   token_ids = (const int*)d_in[0];
    const float* spikes    = (const float*)d_in[1];
    const float* tw        = (const float*)d_in[2];
    float* out = (float*)d_out;

    // Workspace layout:
    //   [counts: B*NRANGE u32] [pairs: NRANGE*B*CAP u32] [part: NRANGE*G2*VR2 u32]
    const size_t counts_elems = (size_t)B_ROWS * NRANGE;                // 8192
    const size_t pairs_elems  = (size_t)NRANGE * B_ROWS * CAP;         // 4.19M
    const size_t part_elems   = (size_t)NRANGE * G2 * VR2;             // 2.05M
    const size_t need = (counts_elems + pairs_elems + part_elems) * 4; // 25 MB

    if (ws_size >= need) {
        unsigned* counts = (unsigned*)d_ws;
        unsigned* pairs  = counts + counts_elems;
        unsigned* part   = pairs + pairs_elems;

        stdp_scan_pack<<<B_ROWS, 512, 0, stream>>>(token_ids, spikes,
                                                   counts, pairs);
        stdp_bin<<<NRANGE * G2, 512, 0, stream>>>(counts, pairs, part);
        stdp_reduce<<<(VOCAB_N / 2 + 255) / 256, 256, 0, stream>>>(tw, part, out);
    } else {
        // Fallback: direct global atomics.
        hipMemsetAsync(out, 0, (size_t)out_size * sizeof(float), stream);
        stdp_scan_scatter<<<B_ROWS, 512, 0, stream>>>(token_ids, spikes, out);
        stdp_finalize<<<(out_size + 255) / 256, 256, 0, stream>>>(tw, out,
                                                                  out_size);
    }
}